// Round 2
// 1016.354 us; speedup vs baseline: 1.0462x; 1.0462x over previous
//
#include <hip/hip_runtime.h>

// Problem constants (from reference setup_inputs)
#define N_NODES 50000
#define N_EDGES 800000
#define XF 512
#define EF 64
#define UF 128
#define HS 1024
#define CIN 832           // 512 + 3*64 + 128
#define EPS_BN 1e-5f
#define M_PAD 50048       // 391 * 128  (GEMM row padding)
#define NSCAN 50176       // 196 * 256  (scan padding)

typedef __bf16 bf16x8 __attribute__((ext_vector_type(8)));
typedef short s16x8 __attribute__((ext_vector_type(8)));
typedef short s16x4 __attribute__((ext_vector_type(4)));
typedef float f32x4 __attribute__((ext_vector_type(4)));

__device__ __forceinline__ short f2bf(float f) {
  unsigned u = __float_as_uint(f);
  u += 0x7FFFu + ((u >> 16) & 1u);   // round-to-nearest-even (finite inputs)
  return (short)(u >> 16);
}
__device__ __forceinline__ float bf2f(short s) {
  return __uint_as_float(((unsigned)(unsigned short)s) << 16);
}

// async global->LDS, 16B per lane; LDS dest must be uniform-base + lane*16
#define ASYNC_CP(gp, lp)                                                      \
  __builtin_amdgcn_global_load_lds(                                           \
      (__attribute__((address_space(1))) void*)(gp),                          \
      (__attribute__((address_space(3))) void*)(lp), 16, 0, 0)

// ---------------------------------------------------------------------------
// 1) Edge histogram over destination node (int atomics, 1 per edge)
// ---------------------------------------------------------------------------
__global__ void hist_kernel(const int* __restrict__ col,
                            int* __restrict__ hist) {
  int e = blockIdx.x * 256 + threadIdx.x;   // grid exactly E
  atomicAdd(&hist[col[e]], 1);
}

// ---------------------------------------------------------------------------
// 2) 3-phase exclusive scan over NSCAN counts
// ---------------------------------------------------------------------------
__global__ void scan1_kernel(const int* __restrict__ hist,
                             int* __restrict__ starts,
                             int* __restrict__ bsum) {
  __shared__ int tmp[256];
  int i = blockIdx.x * 256 + threadIdx.x;
  int v = hist[i];
  tmp[threadIdx.x] = v;
  __syncthreads();
#pragma unroll
  for (int o = 1; o < 256; o <<= 1) {
    int t = (threadIdx.x >= o) ? tmp[threadIdx.x - o] : 0;
    __syncthreads();
    tmp[threadIdx.x] += t;
    __syncthreads();
  }
  starts[i] = tmp[threadIdx.x] - v;   // exclusive
  if (threadIdx.x == 255) bsum[blockIdx.x] = tmp[255];
}

__global__ void scan2_kernel(const int* __restrict__ bsum,
                             int* __restrict__ boff) {
  __shared__ int tmp[256];
  int v = (threadIdx.x < NSCAN / 256) ? bsum[threadIdx.x] : 0;
  tmp[threadIdx.x] = v;
  __syncthreads();
#pragma unroll
  for (int o = 1; o < 256; o <<= 1) {
    int t = (threadIdx.x >= o) ? tmp[threadIdx.x - o] : 0;
    __syncthreads();
    tmp[threadIdx.x] += t;
    __syncthreads();
  }
  boff[threadIdx.x] = tmp[threadIdx.x] - v;
}

__global__ void scan3_kernel(int* __restrict__ starts,
                             const int* __restrict__ boff,
                             int* __restrict__ cursor) {
  int i = blockIdx.x * 256 + threadIdx.x;
  int s = starts[i] + boff[blockIdx.x];
  starts[i] = s;
  cursor[i] = s;
}

// ---------------------------------------------------------------------------
// 3) Placement: edge ids sorted (bucketed) by destination node
// ---------------------------------------------------------------------------
__global__ void place_kernel(const int* __restrict__ col,
                             int* __restrict__ cursor,
                             int* __restrict__ sortedEid) {
  int e = blockIdx.x * 256 + threadIdx.x;   // grid exactly E
  int c = col[e];
  int pos = atomicAdd(&cursor[c], 1);
  sortedEid[pos] = e;
}

// ---------------------------------------------------------------------------
// 4) Segmented reduce: one wave per node; lane = feature. Each iteration the
//    wave reads one contiguous 256B edge row. Writes max/mean/sum cols of h.
// ---------------------------------------------------------------------------
__global__ __launch_bounds__(256) void edge_reduce_kernel(
    const float* __restrict__ ea, const int* __restrict__ sortedEid,
    const int* __restrict__ hist, const int* __restrict__ starts,
    short* __restrict__ h) {
  int node = blockIdx.x * 4 + (threadIdx.x >> 6);   // grid 12500 -> node<50000
  int lane = threadIdx.x & 63;
  int deg = hist[node];
  int st = starts[node];
  float s = 0.f, mx = -3.0e38f;
  for (int i = 0; i < deg; ++i) {
    int e = sortedEid[st + i];
    float v = ea[(size_t)e * EF + lane];
    s += v;
    mx = fmaxf(mx, v);
  }
  size_t base = (size_t)node * CIN;
  h[base + 640 + lane] = f2bf(deg ? mx : 0.f);
  h[base + 704 + lane] = f2bf(deg ? s / (float)deg : 0.f);
  h[base + 768 + lane] = f2bf(s);
}

// ---------------------------------------------------------------------------
// 5) Assemble x / u[batch] columns of h (bf16), zero pad rows entirely
// ---------------------------------------------------------------------------
__global__ __launch_bounds__(256) void assemble_xu_kernel(
    const float* __restrict__ x, const float* __restrict__ u,
    const int* __restrict__ batch, short* __restrict__ h) {
  int n = blockIdx.x;
  int t = threadIdx.x;
  size_t base = (size_t)n * CIN;
  if (n >= N_NODES) {           // pad rows: zero all 832 cols
    if (t < 208) *(s16x4*)&h[base + 4 * t] = (s16x4){0, 0, 0, 0};
    return;
  }
  if (t < 128) {
    const float4 v = *(const float4*)&x[(size_t)n * XF + 4 * t];
    *(s16x4*)&h[base + 4 * t] =
        (s16x4){f2bf(v.x), f2bf(v.y), f2bf(v.z), f2bf(v.w)};
  } else if (t < 160) {
    int c = 4 * (t - 128);
    const float4 v = *(const float4*)&u[batch[n] * UF + c];
    *(s16x4*)&h[base + XF + c] =
        (s16x4){f2bf(v.x), f2bf(v.y), f2bf(v.z), f2bf(v.w)};
  }
}

// ---------------------------------------------------------------------------
// 6) fp32 -> bf16 weight cast
// ---------------------------------------------------------------------------
__global__ void cast_kernel(const float* __restrict__ w, short* __restrict__ o,
                            int n) {
  int i = blockIdx.x * 256 + threadIdx.x;
  if (i < n) o[i] = f2bf(w[i]);
}

// ---------------------------------------------------------------------------
// 7) GEMM: C[M,1024] = A[M,K] @ B[1024,K]^T + bias, bf16 in, fused BN stats.
//    128x128 tile, 4 waves of 64x64 (4x4 MFMA 16x16x32), BK=32.
//    (a) double-buffered LDS prefetch (T3 minimum 2-phase): stage tile t+1
//    while computing tile t -> the vmcnt(0) drain at the barrier waits on a
//    load issued one compute-phase earlier, not the same iteration.
//    (b) bijective XCD swizzle (T1/m204): each XCD owns a contiguous run of
//    A row-panels with all 8 col-panels -> A panel fetched ~once per XCD L2
//    instead of 8x from LLC/HBM.
// ---------------------------------------------------------------------------
template <bool BF16OUT>
__global__ __launch_bounds__(256) void gemm_bt(
    const short* __restrict__ A, const short* __restrict__ B,
    const float* __restrict__ bias, void* __restrict__ outp, int K,
    int M_store, int M_stat, float* __restrict__ sums) {
  __shared__ short aT[2 * 128 * 32];
  __shared__ short bT[2 * 128 * 32];
  const int tid = threadIdx.x;
  const int lane = tid & 63;
  const int wave = tid >> 6;
  // XCD-aware bijective swizzle: grid = dim3(8, nY), total = 8*nY blocks.
  // Default dispatch puts linear id l on XCD l%8. Remap so XCD c computes
  // g in [c*nY, (c+1)*nY): ~nY/8 consecutive m-panels x all 8 n-panels.
  const int nY = gridDim.y;
  const int l = blockIdx.y * 8 + blockIdx.x;
  const int g = (l & 7) * nY + (l >> 3);
  const int m0 = (g >> 3) * 128;
  const int n0 = (g & 7) * 128;
  const int wm = (wave & 1) * 64;
  const int wn = (wave >> 1) * 64;
  const int lm = lane & 15;
  const int lk8 = (lane >> 4) * 8;

  f32x4 acc[4][4];
#pragma unroll
  for (int i = 0; i < 4; ++i)
#pragma unroll
    for (int j = 0; j < 4; ++j) acc[i][j] = (f32x4){0.f, 0.f, 0.f, 0.f};

  const int q0 = tid;
  const int q1 = tid + 256;
  const short* ga0 = A + (size_t)(m0 + (q0 >> 2)) * K + (q0 & 3) * 8;
  const short* ga1 = A + (size_t)(m0 + (q1 >> 2)) * K + (q1 & 3) * 8;
  const short* gb0 = B + (size_t)(n0 + (q0 >> 2)) * K + (q0 & 3) * 8;
  const short* gb1 = B + (size_t)(n0 + (q1 >> 2)) * K + (q1 & 3) * 8;
  short* la0 = &aT[q0 * 8];
  short* la1 = &aT[q1 * 8];
  short* lb0 = &bT[q0 * 8];
  short* lb1 = &bT[q1 * 8];

  int aoff[4], boff[4];
#pragma unroll
  for (int t = 0; t < 4; ++t) {
    aoff[t] = (wm + t * 16 + lm) * 32 + lk8;
    boff[t] = (wn + t * 16 + lm) * 32 + lk8;
  }

  // prologue: stage K-tile 0 into buffer 0
  ASYNC_CP(ga0, la0);
  ASYNC_CP(ga1, la1);
  ASYNC_CP(gb0, lb0);
  ASYNC_CP(gb1, lb1);

  int so = 128 * 32;   // stage offset (shorts): buffer for tile t+1
  int ro = 0;          // read offset: buffer holding tile t
  for (int k0 = 32; k0 < K; k0 += 32) {
    // barrier implies vmcnt(0)+lgkmcnt(0): stage(ro) complete, and all waves
    // finished reading buffer 'so' last iteration -> safe to overwrite.
    __syncthreads();
    ASYNC_CP(ga0 + k0, la0 + so);
    ASYNC_CP(ga1 + k0, la1 + so);
    ASYNC_CP(gb0 + k0, lb0 + so);
    ASYNC_CP(gb1 + k0, lb1 + so);
    bf16x8 af[4], bfr[4];
#pragma unroll
    for (int t = 0; t < 4; ++t) {
      af[t] = __builtin_bit_cast(bf16x8, *(const s16x8*)&aT[ro + aoff[t]]);
      bfr[t] = __builtin_bit_cast(bf16x8, *(const s16x8*)&bT[ro + boff[t]]);
    }
#pragma unroll
    for (int i = 0; i < 4; ++i)
#pragma unroll
      for (int j = 0; j < 4; ++j)
        acc[i][j] = __builtin_amdgcn_mfma_f32_16x16x32_bf16(af[i], bfr[j],
                                                            acc[i][j], 0, 0, 0);
    so ^= 128 * 32;
    ro ^= 128 * 32;
  }
  // final tile (no prefetch)
  __syncthreads();
  {
    bf16x8 af[4], bfr[4];
#pragma unroll
    for (int t = 0; t < 4; ++t) {
      af[t] = __builtin_bit_cast(bf16x8, *(const s16x8*)&aT[ro + aoff[t]]);
      bfr[t] = __builtin_bit_cast(bf16x8, *(const s16x8*)&bT[ro + boff[t]]);
    }
#pragma unroll
    for (int i = 0; i < 4; ++i)
#pragma unroll
      for (int j = 0; j < 4; ++j)
        acc[i][j] = __builtin_amdgcn_mfma_f32_16x16x32_bf16(af[i], bfr[j],
                                                            acc[i][j], 0, 0, 0);
  }

  // epilogue: C/D layout col=lane&15, row=(lane>>4)*4+reg  [m89-verified]
  // + fused per-channel sum / sumsq partials for BN (rows < M_stat)
#pragma unroll
  for (int j = 0; j < 4; ++j) {
    const int colg = n0 + wn + j * 16 + lm;
    const float bv = bias[colg];
    float cs = 0.f, cq = 0.f;
#pragma unroll
    for (int i = 0; i < 4; ++i) {
      const int rbase = m0 + wm + i * 16 + (lane >> 4) * 4;
#pragma unroll
      for (int r = 0; r < 4; ++r) {
        const int row = rbase + r;
        const float v = acc[i][j][r] + bv;
        if (row < M_stat) {
          cs += v;
          cq += v * v;
        }
        if (row < M_store) {
          if (BF16OUT)
            ((short*)outp)[(size_t)row * HS + colg] = f2bf(v);
          else
            ((float*)outp)[(size_t)row * HS + colg] = v;
        }
      }
    }
    cs += __shfl_xor(cs, 16);
    cs += __shfl_xor(cs, 32);
    cq += __shfl_xor(cq, 16);
    cq += __shfl_xor(cq, 32);
    if ((lane >> 4) == 0) {
      atomicAdd(&sums[colg], cs);
      atomicAdd(&sums[HS + colg], cq);
    }
  }
}

// ---------------------------------------------------------------------------
// 8) BN finalize: per-channel scale/shift from sums
// ---------------------------------------------------------------------------
__global__ void finalize_kernel(const float* __restrict__ sums,
                                const float* __restrict__ gamma,
                                const float* __restrict__ beta,
                                float* __restrict__ scsh) {
  int c = blockIdx.x * 256 + threadIdx.x;   // grid 4 x 256 = 1024
  const float inv = 1.f / (float)N_NODES;
  float m = sums[c] * inv;
  float var = sums[HS + c] * inv - m * m;   // biased var, matches reference
  float sc = gamma[c] / sqrtf(var + EPS_BN);
  scsh[c] = sc;
  scsh[HS + c] = beta[c] - m * sc;
}

// ---------------------------------------------------------------------------
// 9) BN apply (in place). bf16 variant adds ReLU (layer 1).
// ---------------------------------------------------------------------------
__global__ __launch_bounds__(256) void bn_relu_bf16_kernel(
    short* __restrict__ y, const float* __restrict__ scsh) {
  size_t base = (size_t)blockIdx.x * HS + threadIdx.x * 4;
  int c = threadIdx.x * 4;
  s16x4 v = *(s16x4*)&y[base];
  s16x4 o;
#pragma unroll
  for (int k = 0; k < 4; ++k) {
    float f = bf2f(v[k]) * scsh[c + k] + scsh[HS + c + k];
    o[k] = f2bf(fmaxf(f, 0.f));
  }
  *(s16x4*)&y[base] = o;
}

__global__ __launch_bounds__(256) void bn_f32_kernel(
    float* __restrict__ y, const float* __restrict__ scsh) {
  size_t base = (size_t)blockIdx.x * HS + threadIdx.x * 4;
  int c = threadIdx.x * 4;
  float4 v = *(float4*)&y[base];
  const float4 sc = *(const float4*)&scsh[c];
  const float4 sh = *(const float4*)&scsh[HS + c];
  v.x = v.x * sc.x + sh.x;
  v.y = v.y * sc.y + sh.y;
  v.z = v.z * sc.z + sh.z;
  v.w = v.w * sc.w + sh.w;
  *(float4*)&y[base] = v;
}

// ---------------------------------------------------------------------------
extern "C" void kernel_launch(void* const* d_in, const int* in_sizes, int n_in,
                              void* d_out, int out_size, void* d_ws,
                              size_t ws_size, hipStream_t stream) {
  const float* x = (const float*)d_in[0];
  const float* ea = (const float*)d_in[1];
  const float* u = (const float*)d_in[2];
  const float* w1 = (const float*)d_in[3];
  const float* b1 = (const float*)d_in[4];
  const float* g1 = (const float*)d_in[5];
  const float* be1 = (const float*)d_in[6];
  const float* w2 = (const float*)d_in[7];
  const float* b2 = (const float*)d_in[8];
  const float* g2 = (const float*)d_in[9];
  const float* be2 = (const float*)d_in[10];
  const int* ei = (const int*)d_in[11];
  const int* batch = (const int*)d_in[12];
  float* out = (float*)d_out;
  const int* col = ei + N_EDGES;   // edge_index[1]

  // ---- workspace layout ----
  char* ws = (char*)d_ws;
  float* sums1 = (float*)ws;                     // 2048
  float* sums2 = sums1 + 2048;                   // 2048
  int* hist = (int*)(sums2 + 2048);              // NSCAN
  int* bsum = hist + NSCAN;                      // 256
  // ---- end of zero region ----
  size_t zero_bytes = (size_t)((char*)(bsum + 256) - ws);
  float* scsh = (float*)(bsum + 256);            // 2048
  int* starts = (int*)(scsh + 2048);             // NSCAN
  int* cursor = starts + NSCAN;                  // NSCAN
  int* boff = cursor + NSCAN;                    // 256
  int* sortedEid = boff + 256;                   // N_EDGES
  char* hraw = (char*)(sortedEid + N_EDGES);
  short* h = (short*)(((uintptr_t)hraw + 255) & ~(uintptr_t)255);
  short* w1b = h + (size_t)M_PAD * CIN;
  short* w2b = w1b + (size_t)HS * CIN;
  short* y1 = w2b + (size_t)HS * HS;

  hipMemsetAsync(ws, 0, zero_bytes, stream);

  // edge bucketing
  hist_kernel<<<N_EDGES / 256, 256, 0, stream>>>(col, hist);
  scan1_kernel<<<NSCAN / 256, 256, 0, stream>>>(hist, starts, bsum);
  scan2_kernel<<<1, 256, 0, stream>>>(bsum, boff);
  scan3_kernel<<<NSCAN / 256, 256, 0, stream>>>(starts, boff, cursor);
  place_kernel<<<N_EDGES / 256, 256, 0, stream>>>(col, cursor, sortedEid);

  // h assembly
  assemble_xu_kernel<<<M_PAD, 256, 0, stream>>>(x, u, batch, h);
  edge_reduce_kernel<<<N_NODES / 4, 256, 0, stream>>>(ea, sortedEid, hist,
                                                      starts, h);
  cast_kernel<<<(HS * CIN + 255) / 256, 256, 0, stream>>>(w1, w1b, HS * CIN);
  cast_kernel<<<(HS * HS + 255) / 256, 256, 0, stream>>>(w2, w2b, HS * HS);

  // layer 1
  gemm_bt<true><<<dim3(8, M_PAD / 128), 256, 0, stream>>>(
      h, w1b, b1, y1, CIN, M_PAD, N_NODES, sums1);
  finalize_kernel<<<4, 256, 0, stream>>>(sums1, g1, be1, scsh);
  bn_relu_bf16_kernel<<<N_NODES, 256, 0, stream>>>(y1, scsh);

  // layer 2
  gemm_bt<false><<<dim3(8, M_PAD / 128), 256, 0, stream>>>(
      y1, w2b, b2, out, HS, N_NODES, N_NODES, sums2);
  finalize_kernel<<<4, 256, 0, stream>>>(sums2, g2, be2, scsh);
  bn_f32_kernel<<<N_NODES, 256, 0, stream>>>(out, scsh);
}

// Round 3
// 1011.105 us; speedup vs baseline: 1.0517x; 1.0052x over previous
//
#include <hip/hip_runtime.h>

// Problem constants (from reference setup_inputs)
#define N_NODES 50000
#define N_EDGES 800000
#define XF 512
#define EF 64
#define UF 128
#define HS 1024
#define CIN 832           // 512 + 3*64 + 128
#define EPS_BN 1e-5f
#define M_PAD 50048       // 391 * 128  (GEMM row padding)
#define NSCAN 50176       // 196 * 256  (scan padding)

typedef __bf16 bf16x8 __attribute__((ext_vector_type(8)));
typedef short s16x8 __attribute__((ext_vector_type(8)));
typedef short s16x4 __attribute__((ext_vector_type(4)));
typedef float f32x4 __attribute__((ext_vector_type(4)));

__device__ __forceinline__ short f2bf(float f) {
  unsigned u = __float_as_uint(f);
  u += 0x7FFFu + ((u >> 16) & 1u);   // round-to-nearest-even (finite inputs)
  return (short)(u >> 16);
}
__device__ __forceinline__ float bf2f(short s) {
  return __uint_as_float(((unsigned)(unsigned short)s) << 16);
}

// async global->LDS, 16B per lane; LDS dest must be uniform-base + lane*16
#define ASYNC_CP(gp, lp)                                                      \
  __builtin_amdgcn_global_load_lds(                                           \
      (__attribute__((address_space(1))) void*)(gp),                          \
      (__attribute__((address_space(3))) void*)(lp), 16, 0, 0)

// ---------------------------------------------------------------------------
// 1) Edge histogram over destination node (int atomics, 1 per edge)
// ---------------------------------------------------------------------------
__global__ void hist_kernel(const int* __restrict__ col,
                            int* __restrict__ hist) {
  int e = blockIdx.x * 256 + threadIdx.x;   // grid exactly E
  atomicAdd(&hist[col[e]], 1);
}

// ---------------------------------------------------------------------------
// 2) 3-phase exclusive scan over NSCAN counts
// ---------------------------------------------------------------------------
__global__ void scan1_kernel(const int* __restrict__ hist,
                             int* __restrict__ starts,
                             int* __restrict__ bsum) {
  __shared__ int tmp[256];
  int i = blockIdx.x * 256 + threadIdx.x;
  int v = hist[i];
  tmp[threadIdx.x] = v;
  __syncthreads();
#pragma unroll
  for (int o = 1; o < 256; o <<= 1) {
    int t = (threadIdx.x >= o) ? tmp[threadIdx.x - o] : 0;
    __syncthreads();
    tmp[threadIdx.x] += t;
    __syncthreads();
  }
  starts[i] = tmp[threadIdx.x] - v;   // exclusive
  if (threadIdx.x == 255) bsum[blockIdx.x] = tmp[255];
}

__global__ void scan2_kernel(const int* __restrict__ bsum,
                             int* __restrict__ boff) {
  __shared__ int tmp[256];
  int v = (threadIdx.x < NSCAN / 256) ? bsum[threadIdx.x] : 0;
  tmp[threadIdx.x] = v;
  __syncthreads();
#pragma unroll
  for (int o = 1; o < 256; o <<= 1) {
    int t = (threadIdx.x >= o) ? tmp[threadIdx.x - o] : 0;
    __syncthreads();
    tmp[threadIdx.x] += t;
    __syncthreads();
  }
  boff[threadIdx.x] = tmp[threadIdx.x] - v;
}

__global__ void scan3_kernel(int* __restrict__ starts,
                             const int* __restrict__ boff,
                             int* __restrict__ cursor) {
  int i = blockIdx.x * 256 + threadIdx.x;
  int s = starts[i] + boff[blockIdx.x];
  starts[i] = s;
  cursor[i] = s;
}

// ---------------------------------------------------------------------------
// 3) Placement: edge ids sorted (bucketed) by destination node
// ---------------------------------------------------------------------------
__global__ void place_kernel(const int* __restrict__ col,
                             int* __restrict__ cursor,
                             int* __restrict__ sortedEid) {
  int e = blockIdx.x * 256 + threadIdx.x;   // grid exactly E
  int c = col[e];
  int pos = atomicAdd(&cursor[c], 1);
  sortedEid[pos] = e;
}

// ---------------------------------------------------------------------------
// 4) Segmented reduce: one wave per node; lane = feature. Each iteration the
//    wave reads one contiguous 256B edge row. Writes max/mean/sum cols of h.
// ---------------------------------------------------------------------------
__global__ __launch_bounds__(256) void edge_reduce_kernel(
    const float* __restrict__ ea, const int* __restrict__ sortedEid,
    const int* __restrict__ hist, const int* __restrict__ starts,
    short* __restrict__ h) {
  int node = blockIdx.x * 4 + (threadIdx.x >> 6);   // grid 12500 -> node<50000
  int lane = threadIdx.x & 63;
  int deg = hist[node];
  int st = starts[node];
  float s = 0.f, mx = -3.0e38f;
  for (int i = 0; i < deg; ++i) {
    int e = sortedEid[st + i];
    float v = ea[(size_t)e * EF + lane];
    s += v;
    mx = fmaxf(mx, v);
  }
  size_t base = (size_t)node * CIN;
  h[base + 640 + lane] = f2bf(deg ? mx : 0.f);
  h[base + 704 + lane] = f2bf(deg ? s / (float)deg : 0.f);
  h[base + 768 + lane] = f2bf(s);
}

// ---------------------------------------------------------------------------
// 5) Assemble x / u[batch] columns of h (bf16), zero pad rows entirely
// ---------------------------------------------------------------------------
__global__ __launch_bounds__(256) void assemble_xu_kernel(
    const float* __restrict__ x, const float* __restrict__ u,
    const int* __restrict__ batch, short* __restrict__ h) {
  int n = blockIdx.x;
  int t = threadIdx.x;
  size_t base = (size_t)n * CIN;
  if (n >= N_NODES) {           // pad rows: zero all 832 cols
    if (t < 208) *(s16x4*)&h[base + 4 * t] = (s16x4){0, 0, 0, 0};
    return;
  }
  if (t < 128) {
    const float4 v = *(const float4*)&x[(size_t)n * XF + 4 * t];
    *(s16x4*)&h[base + 4 * t] =
        (s16x4){f2bf(v.x), f2bf(v.y), f2bf(v.z), f2bf(v.w)};
  } else if (t < 160) {
    int c = 4 * (t - 128);
    const float4 v = *(const float4*)&u[batch[n] * UF + c];
    *(s16x4*)&h[base + XF + c] =
        (s16x4){f2bf(v.x), f2bf(v.y), f2bf(v.z), f2bf(v.w)};
  }
}

// ---------------------------------------------------------------------------
// 6) fp32 -> bf16 weight cast
// ---------------------------------------------------------------------------
__global__ void cast_kernel(const float* __restrict__ w, short* __restrict__ o,
                            int n) {
  int i = blockIdx.x * 256 + threadIdx.x;
  if (i < n) o[i] = f2bf(w[i]);
}

// ---------------------------------------------------------------------------
// 7) GEMM: C[M,1024] = A[M,K] @ B[1024,K]^T + bias, bf16 in, fused BN stats.
//    128x128 tile, 4 waves of 64x64 (4x4 MFMA 16x16x32), BK=32.
//    Round 3: depth-2 prefetch with COUNTED vmcnt (T4): 3 LDS buffers, raw
//    s_barrier preceded by s_waitcnt vmcnt(4) (never 0 in main loop) -> tile
//    t+1's loads stay in flight across the barrier; tile t's loads were
//    issued two compute phases earlier. Stage of t+2 is issued AFTER the
//    barrier: the barrier proves all waves finished reading buffer (t-1)%3
//    (its ds_reads were consumed by MFMAs before barrier), which is exactly
//    the buffer t+2 overwrites.
//    Plus bijective XCD swizzle (T1/m204) from round 2 (FETCH 405->86MB).
// ---------------------------------------------------------------------------
template <bool BF16OUT>
__global__ __launch_bounds__(256) void gemm_bt(
    const short* __restrict__ A, const short* __restrict__ B,
    const float* __restrict__ bias, void* __restrict__ outp, int K,
    int M_store, int M_stat, float* __restrict__ sums) {
  constexpr int TB = 128 * 32;     // one K-tile buffer, in shorts
  __shared__ short aT[3 * TB];
  __shared__ short bT[3 * TB];
  const int tid = threadIdx.x;
  const int lane = tid & 63;
  const int wave = tid >> 6;
  // XCD-aware bijective swizzle: grid = dim3(8, nY), total = 8*nY blocks.
  const int nY = gridDim.y;
  const int l = blockIdx.y * 8 + blockIdx.x;
  const int g = (l & 7) * nY + (l >> 3);
  const int m0 = (g >> 3) * 128;
  const int n0 = (g & 7) * 128;
  const int wm = (wave & 1) * 64;
  const int wn = (wave >> 1) * 64;
  const int lm = lane & 15;
  const int lk8 = (lane >> 4) * 8;

  f32x4 acc[4][4];
#pragma unroll
  for (int i = 0; i < 4; ++i)
#pragma unroll
    for (int j = 0; j < 4; ++j) acc[i][j] = (f32x4){0.f, 0.f, 0.f, 0.f};

  const int q0 = tid;
  const int q1 = tid + 256;
  const short* ga0 = A + (size_t)(m0 + (q0 >> 2)) * K + (q0 & 3) * 8;
  const short* ga1 = A + (size_t)(m0 + (q1 >> 2)) * K + (q1 & 3) * 8;
  const short* gb0 = B + (size_t)(n0 + (q0 >> 2)) * K + (q0 & 3) * 8;
  const short* gb1 = B + (size_t)(n0 + (q1 >> 2)) * K + (q1 & 3) * 8;
  short* la0 = &aT[q0 * 8];
  short* la1 = &aT[q1 * 8];
  short* lb0 = &bT[q0 * 8];
  short* lb1 = &bT[q1 * 8];

  int aoff[4], boff[4];
#pragma unroll
  for (int t = 0; t < 4; ++t) {
    aoff[t] = (wm + t * 16 + lm) * 32 + lk8;
    boff[t] = (wn + t * 16 + lm) * 32 + lk8;
  }

  // prologue: stage K-tiles 0 and 1 into buffers 0 and 1 (8 loads in flight)
  ASYNC_CP(ga0, la0);
  ASYNC_CP(ga1, la1);
  ASYNC_CP(gb0, lb0);
  ASYNC_CP(gb1, lb1);
  ASYNC_CP(ga0 + 32, la0 + TB);
  ASYNC_CP(ga1 + 32, la1 + TB);
  ASYNC_CP(gb0 + 32, lb0 + TB);
  ASYNC_CP(gb1 + 32, lb1 + TB);

  const int nt = K / 32;
  int br = 0;        // buffer holding tile t (read now)
  int bf = TB;       // buffer holding tile t+1 (in flight)
  int bs = 2 * TB;   // buffer to stage tile t+2 into
  for (int t = 0; t < nt - 1; ++t) {
    // wait only for tile t's 4 loads (oldest); tile t+1's stay in flight
    asm volatile("s_waitcnt vmcnt(4)" ::: "memory");
    __builtin_amdgcn_s_barrier();
    asm volatile("" ::: "memory");
    if (t + 2 < nt) {
      const int k0s = (t + 2) * 32;
      ASYNC_CP(ga0 + k0s, la0 + bs);
      ASYNC_CP(ga1 + k0s, la1 + bs);
      ASYNC_CP(gb0 + k0s, lb0 + bs);
      ASYNC_CP(gb1 + k0s, lb1 + bs);
    }
    bf16x8 af[4], bfr[4];
#pragma unroll
    for (int q = 0; q < 4; ++q) {
      af[q] = __builtin_bit_cast(bf16x8, *(const s16x8*)&aT[br + aoff[q]]);
      bfr[q] = __builtin_bit_cast(bf16x8, *(const s16x8*)&bT[br + boff[q]]);
    }
#pragma unroll
    for (int i = 0; i < 4; ++i)
#pragma unroll
      for (int j = 0; j < 4; ++j)
        acc[i][j] = __builtin_amdgcn_mfma_f32_16x16x32_bf16(af[i], bfr[j],
                                                            acc[i][j], 0, 0, 0);
    const int tmp = br;
    br = bf;
    bf = bs;
    bs = tmp;
  }
  // final tile: drain everything
  asm volatile("s_waitcnt vmcnt(0)" ::: "memory");
  __builtin_amdgcn_s_barrier();
  asm volatile("" ::: "memory");
  {
    bf16x8 af[4], bfr[4];
#pragma unroll
    for (int q = 0; q < 4; ++q) {
      af[q] = __builtin_bit_cast(bf16x8, *(const s16x8*)&aT[br + aoff[q]]);
      bfr[q] = __builtin_bit_cast(bf16x8, *(const s16x8*)&bT[br + boff[q]]);
    }
#pragma unroll
    for (int i = 0; i < 4; ++i)
#pragma unroll
      for (int j = 0; j < 4; ++j)
        acc[i][j] = __builtin_amdgcn_mfma_f32_16x16x32_bf16(af[i], bfr[j],
                                                            acc[i][j], 0, 0, 0);
  }

  // epilogue: C/D layout col=lane&15, row=(lane>>4)*4+reg  [m89-verified]
  // + fused per-channel sum / sumsq partials for BN (rows < M_stat)
#pragma unroll
  for (int j = 0; j < 4; ++j) {
    const int colg = n0 + wn + j * 16 + lm;
    const float bv = bias[colg];
    float cs = 0.f, cq = 0.f;
#pragma unroll
    for (int i = 0; i < 4; ++i) {
      const int rbase = m0 + wm + i * 16 + (lane >> 4) * 4;
#pragma unroll
      for (int r = 0; r < 4; ++r) {
        const int row = rbase + r;
        const float v = acc[i][j][r] + bv;
        if (row < M_stat) {
          cs += v;
          cq += v * v;
        }
        if (row < M_store) {
          if (BF16OUT)
            ((short*)outp)[(size_t)row * HS + colg] = f2bf(v);
          else
            ((float*)outp)[(size_t)row * HS + colg] = v;
        }
      }
    }
    cs += __shfl_xor(cs, 16);
    cs += __shfl_xor(cs, 32);
    cq += __shfl_xor(cq, 16);
    cq += __shfl_xor(cq, 32);
    if ((lane >> 4) == 0) {
      atomicAdd(&sums[colg], cs);
      atomicAdd(&sums[HS + colg], cq);
    }
  }
}

// ---------------------------------------------------------------------------
// 8) BN finalize: per-channel scale/shift from sums
// ---------------------------------------------------------------------------
__global__ void finalize_kernel(const float* __restrict__ sums,
                                const float* __restrict__ gamma,
                                const float* __restrict__ beta,
                                float* __restrict__ scsh) {
  int c = blockIdx.x * 256 + threadIdx.x;   // grid 4 x 256 = 1024
  const float inv = 1.f / (float)N_NODES;
  float m = sums[c] * inv;
  float var = sums[HS + c] * inv - m * m;   // biased var, matches reference
  float sc = gamma[c] / sqrtf(var + EPS_BN);
  scsh[c] = sc;
  scsh[HS + c] = beta[c] - m * sc;
}

// ---------------------------------------------------------------------------
// 9) BN apply (in place). bf16 variant adds ReLU (layer 1).
// ---------------------------------------------------------------------------
__global__ __launch_bounds__(256) void bn_relu_bf16_kernel(
    short* __restrict__ y, const float* __restrict__ scsh) {
  size_t base = (size_t)blockIdx.x * HS + threadIdx.x * 4;
  int c = threadIdx.x * 4;
  s16x4 v = *(s16x4*)&y[base];
  s16x4 o;
#pragma unroll
  for (int k = 0; k < 4; ++k) {
    float f = bf2f(v[k]) * scsh[c + k] + scsh[HS + c + k];
    o[k] = f2bf(fmaxf(f, 0.f));
  }
  *(s16x4*)&y[base] = o;
}

__global__ __launch_bounds__(256) void bn_f32_kernel(
    float* __restrict__ y, const float* __restrict__ scsh) {
  size_t base = (size_t)blockIdx.x * HS + threadIdx.x * 4;
  int c = threadIdx.x * 4;
  float4 v = *(float4*)&y[base];
  const float4 sc = *(const float4*)&scsh[c];
  const float4 sh = *(const float4*)&scsh[HS + c];
  v.x = v.x * sc.x + sh.x;
  v.y = v.y * sc.y + sh.y;
  v.z = v.z * sc.z + sh.z;
  v.w = v.w * sc.w + sh.w;
  *(float4*)&y[base] = v;
}

// ---------------------------------------------------------------------------
extern "C" void kernel_launch(void* const* d_in, const int* in_sizes, int n_in,
                              void* d_out, int out_size, void* d_ws,
                              size_t ws_size, hipStream_t stream) {
  const float* x = (const float*)d_in[0];
  const float* ea = (const float*)d_in[1];
  const float* u = (const float*)d_in[2];
  const float* w1 = (const float*)d_in[3];
  const float* b1 = (const float*)d_in[4];
  const float* g1 = (const float*)d_in[5];
  const float* be1 = (const float*)d_in[6];
  const float* w2 = (const float*)d_in[7];
  const float* b2 = (const float*)d_in[8];
  const float* g2 = (const float*)d_in[9];
  const float* be2 = (const float*)d_in[10];
  const int* ei = (const int*)d_in[11];
  const int* batch = (const int*)d_in[12];
  float* out = (float*)d_out;
  const int* col = ei + N_EDGES;   // edge_index[1]

  // ---- workspace layout ----
  char* ws = (char*)d_ws;
  float* sums1 = (float*)ws;                     // 2048
  float* sums2 = sums1 + 2048;                   // 2048
  int* hist = (int*)(sums2 + 2048);              // NSCAN
  int* bsum = hist + NSCAN;                      // 256
  // ---- end of zero region ----
  size_t zero_bytes = (size_t)((char*)(bsum + 256) - ws);
  float* scsh = (float*)(bsum + 256);            // 2048
  int* starts = (int*)(scsh + 2048);             // NSCAN
  int* cursor = starts + NSCAN;                  // NSCAN
  int* boff = cursor + NSCAN;                    // 256
  int* sortedEid = boff + 256;                   // N_EDGES
  char* hraw = (char*)(sortedEid + N_EDGES);
  short* h = (short*)(((uintptr_t)hraw + 255) & ~(uintptr_t)255);
  short* w1b = h + (size_t)M_PAD * CIN;
  short* w2b = w1b + (size_t)HS * CIN;
  short* y1 = w2b + (size_t)HS * HS;

  hipMemsetAsync(ws, 0, zero_bytes, stream);

  // edge bucketing
  hist_kernel<<<N_EDGES / 256, 256, 0, stream>>>(col, hist);
  scan1_kernel<<<NSCAN / 256, 256, 0, stream>>>(hist, starts, bsum);
  scan2_kernel<<<1, 256, 0, stream>>>(bsum, boff);
  scan3_kernel<<<NSCAN / 256, 256, 0, stream>>>(starts, boff, cursor);
  place_kernel<<<N_EDGES / 256, 256, 0, stream>>>(col, cursor, sortedEid);

  // h assembly
  assemble_xu_kernel<<<M_PAD, 256, 0, stream>>>(x, u, batch, h);
  edge_reduce_kernel<<<N_NODES / 4, 256, 0, stream>>>(ea, sortedEid, hist,
                                                      starts, h);
  cast_kernel<<<(HS * CIN + 255) / 256, 256, 0, stream>>>(w1, w1b, HS * CIN);
  cast_kernel<<<(HS * HS + 255) / 256, 256, 0, stream>>>(w2, w2b, HS * HS);

  // layer 1
  gemm_bt<true><<<dim3(8, M_PAD / 128), 256, 0, stream>>>(
      h, w1b, b1, y1, CIN, M_PAD, N_NODES, sums1);
  finalize_kernel<<<4, 256, 0, stream>>>(sums1, g1, be1, scsh);
  bn_relu_bf16_kernel<<<N_NODES, 256, 0, stream>>>(y1, scsh);

  // layer 2
  gemm_bt<false><<<dim3(8, M_PAD / 128), 256, 0, stream>>>(
      y1, w2b, b2, out, HS, N_NODES, N_NODES, sums2);
  finalize_kernel<<<4, 256, 0, stream>>>(sums2, g2, be2, scsh);
  bn_f32_kernel<<<N_NODES, 256, 0, stream>>>(out, scsh);
}

// Round 4
// 940.403 us; speedup vs baseline: 1.1307x; 1.0752x over previous
//
#include <hip/hip_runtime.h>

// Problem constants (from reference setup_inputs)
#define N_NODES 50000
#define N_EDGES 800000
#define XF 512
#define EF 64
#define UF 128
#define HS 1024
#define CIN 832           // 512 + 3*64 + 128
#define EPS_BN 1e-5f
#define M_PAD 50048       // 391 * 128  (GEMM row padding)
#define NSCAN 50176       // 196 * 256  (scan padding)

typedef __bf16 bf16x8 __attribute__((ext_vector_type(8)));
typedef short s16x8 __attribute__((ext_vector_type(8)));
typedef short s16x4 __attribute__((ext_vector_type(4)));
typedef float f32x4 __attribute__((ext_vector_type(4)));

__device__ __forceinline__ short f2bf(float f) {
  unsigned u = __float_as_uint(f);
  u += 0x7FFFu + ((u >> 16) & 1u);   // round-to-nearest-even (finite inputs)
  return (short)(u >> 16);
}
__device__ __forceinline__ float bf2f(short s) {
  return __uint_as_float(((unsigned)(unsigned short)s) << 16);
}

// async global->LDS, 16B per lane; LDS dest must be uniform-base + lane*16
#define ASYNC_CP(gp, lp)                                                      \
  __builtin_amdgcn_global_load_lds(                                           \
      (__attribute__((address_space(1))) void*)(gp),                          \
      (__attribute__((address_space(3))) void*)(lp), 16, 0, 0)

// ---------------------------------------------------------------------------
// 1) Edge histogram over destination node (int atomics, 1 per edge)
// ---------------------------------------------------------------------------
__global__ void hist_kernel(const int* __restrict__ col,
                            int* __restrict__ hist) {
  int e = blockIdx.x * 256 + threadIdx.x;   // grid exactly E
  atomicAdd(&hist[col[e]], 1);
}

// ---------------------------------------------------------------------------
// 2) 3-phase exclusive scan over NSCAN counts
// ---------------------------------------------------------------------------
__global__ void scan1_kernel(const int* __restrict__ hist,
                             int* __restrict__ starts,
                             int* __restrict__ bsum) {
  __shared__ int tmp[256];
  int i = blockIdx.x * 256 + threadIdx.x;
  int v = hist[i];
  tmp[threadIdx.x] = v;
  __syncthreads();
#pragma unroll
  for (int o = 1; o < 256; o <<= 1) {
    int t = (threadIdx.x >= o) ? tmp[threadIdx.x - o] : 0;
    __syncthreads();
    tmp[threadIdx.x] += t;
    __syncthreads();
  }
  starts[i] = tmp[threadIdx.x] - v;   // exclusive
  if (threadIdx.x == 255) bsum[blockIdx.x] = tmp[255];
}

__global__ void scan2_kernel(const int* __restrict__ bsum,
                             int* __restrict__ boff) {
  __shared__ int tmp[256];
  int v = (threadIdx.x < NSCAN / 256) ? bsum[threadIdx.x] : 0;
  tmp[threadIdx.x] = v;
  __syncthreads();
#pragma unroll
  for (int o = 1; o < 256; o <<= 1) {
    int t = (threadIdx.x >= o) ? tmp[threadIdx.x - o] : 0;
    __syncthreads();
    tmp[threadIdx.x] += t;
    __syncthreads();
  }
  boff[threadIdx.x] = tmp[threadIdx.x] - v;
}

__global__ void scan3_kernel(int* __restrict__ starts,
                             const int* __restrict__ boff,
                             int* __restrict__ cursor) {
  int i = blockIdx.x * 256 + threadIdx.x;
  int s = starts[i] + boff[blockIdx.x];
  starts[i] = s;
  cursor[i] = s;
}

// ---------------------------------------------------------------------------
// 3) Placement: edge ids sorted (bucketed) by destination node
// ---------------------------------------------------------------------------
__global__ void place_kernel(const int* __restrict__ col,
                             int* __restrict__ cursor,
                             int* __restrict__ sortedEid) {
  int e = blockIdx.x * 256 + threadIdx.x;   // grid exactly E
  int c = col[e];
  int pos = atomicAdd(&cursor[c], 1);
  sortedEid[pos] = e;
}

// ---------------------------------------------------------------------------
// 4) Segmented reduce: one wave per node; lane = feature. Round 4: preload up
//    to 64 edge ids lane-parallel, shfl-broadcast them, unroll x4 so 4
//    independent ea-row loads are in flight (was: serial eid->row chain).
// ---------------------------------------------------------------------------
__global__ __launch_bounds__(256) void edge_reduce_kernel(
    const float* __restrict__ ea, const int* __restrict__ sortedEid,
    const int* __restrict__ hist, const int* __restrict__ starts,
    short* __restrict__ h) {
  int node = blockIdx.x * 4 + (threadIdx.x >> 6);   // grid 12500 -> node<50000
  int lane = threadIdx.x & 63;
  int deg = hist[node];
  int st = starts[node];
  float s = 0.f, mx = -3.0e38f;
  for (int base = 0; base < deg; base += 64) {
    int nc = deg - base;
    if (nc > 64) nc = 64;
    int el = (lane < nc) ? sortedEid[st + base + lane] : 0;
    int i = 0;
    for (; i + 4 <= nc; i += 4) {
      int e0 = __shfl(el, i);
      int e1 = __shfl(el, i + 1);
      int e2 = __shfl(el, i + 2);
      int e3 = __shfl(el, i + 3);
      float v0 = ea[(size_t)e0 * EF + lane];
      float v1 = ea[(size_t)e1 * EF + lane];
      float v2 = ea[(size_t)e2 * EF + lane];
      float v3 = ea[(size_t)e3 * EF + lane];
      s += (v0 + v1) + (v2 + v3);
      mx = fmaxf(mx, fmaxf(fmaxf(v0, v1), fmaxf(v2, v3)));
    }
    for (; i < nc; ++i) {
      int e = __shfl(el, i);
      float v = ea[(size_t)e * EF + lane];
      s += v;
      mx = fmaxf(mx, v);
    }
  }
  size_t base = (size_t)node * CIN;
  h[base + 640 + lane] = f2bf(deg ? mx : 0.f);
  h[base + 704 + lane] = f2bf(deg ? s / (float)deg : 0.f);
  h[base + 768 + lane] = f2bf(s);
}

// ---------------------------------------------------------------------------
// 5) h assembly, flat fully-coalesced kernels (round 4: split from the old
//    assemble_xu which had 37% idle lanes)
// ---------------------------------------------------------------------------
__global__ __launch_bounds__(256) void cast_x_kernel(
    const float* __restrict__ x, short* __restrict__ h) {
  int idx = blockIdx.x * 256 + threadIdx.x;   // grid 25000 -> N_NODES*128
  int n = idx >> 7;
  int c4 = (idx & 127) * 4;
  const float4 v = *(const float4*)&x[(size_t)n * XF + c4];
  *(s16x4*)&h[(size_t)n * CIN + c4] =
      (s16x4){f2bf(v.x), f2bf(v.y), f2bf(v.z), f2bf(v.w)};
}

__global__ __launch_bounds__(256) void cast_u_kernel(
    const float* __restrict__ u, const int* __restrict__ batch,
    short* __restrict__ h) {
  int idx = blockIdx.x * 256 + threadIdx.x;   // grid 6250 -> N_NODES*32
  int n = idx >> 5;
  int c4 = (idx & 31) * 4;
  const float4 v = *(const float4*)&u[(size_t)batch[n] * UF + c4];
  *(s16x4*)&h[(size_t)n * CIN + XF + c4] =
      (s16x4){f2bf(v.x), f2bf(v.y), f2bf(v.z), f2bf(v.w)};
}

__global__ void pad_kernel(short* __restrict__ h) {
  int idx = blockIdx.x * 256 + threadIdx.x;   // 48 pad rows * 832 / 8 = 4992
  if (idx < (M_PAD - N_NODES) * CIN / 8)
    *(s16x8*)&h[(size_t)N_NODES * CIN + (size_t)idx * 8] =
        (s16x8){0, 0, 0, 0, 0, 0, 0, 0};
}

// ---------------------------------------------------------------------------
// 6) fp32 -> bf16 weight cast (both weights in one launch)
// ---------------------------------------------------------------------------
__global__ void cast2_kernel(const float* __restrict__ w1,
                             const float* __restrict__ w2,
                             short* __restrict__ o1, short* __restrict__ o2) {
  int i = blockIdx.x * 256 + threadIdx.x;   // grid HS*HS/256
  if (i < HS * CIN) o1[i] = f2bf(w1[i]);
  o2[i] = f2bf(w2[i]);
}

// ---------------------------------------------------------------------------
// 7) GEMM: C[M,1024] = A[M,K] @ B[1024,K]^T + bias, bf16 in, fused BN stats.
//    128x128 tile, 4 waves of 64x64 (4x4 MFMA 16x16x32), BK=32.
//    Round-2 double-buffered loop (best measured) + round-4 LDS swizzle:
//    the read pattern row*64B + (lane>>4)*16B is an 8-way bank conflict per
//    16-lane service group. Involution: slot' = slot ^ ((row>>1)&3) spreads
//    each group across all 8 (half,slot) bank cells -> 2-way (free, m136).
//    Per rule #21: LDS dest stays LINEAR (global_load_lds), the global
//    SOURCE chunk is inverse-permuted, the READ offset applies the same XOR.
//    Key (row>>1)&3 == (lm>>1)&3 on the read side (wm,16t are 0 mod 8... mod
//    4 after >>1), and ((q>>2)>>1)&3 == (q>>3)&3 on the stage side.
//    Plus bijective XCD swizzle (T1/m204) from round 2 (FETCH 405->86MB).
// ---------------------------------------------------------------------------
template <bool BF16OUT>
__global__ __launch_bounds__(256) void gemm_bt(
    const short* __restrict__ A, const short* __restrict__ B,
    const float* __restrict__ bias, void* __restrict__ outp, int K,
    int M_store, int M_stat, float* __restrict__ sums) {
  __shared__ short aT[2 * 128 * 32];
  __shared__ short bT[2 * 128 * 32];
  const int tid = threadIdx.x;
  const int lane = tid & 63;
  const int wave = tid >> 6;
  // XCD-aware bijective swizzle: grid = dim3(8, nY), total = 8*nY blocks.
  const int nY = gridDim.y;
  const int l = blockIdx.y * 8 + blockIdx.x;
  const int g = (l & 7) * nY + (l >> 3);
  const int m0 = (g >> 3) * 128;
  const int n0 = (g & 7) * 128;
  const int wm = (wave & 1) * 64;
  const int wn = (wave >> 1) * 64;
  const int lm = lane & 15;

  f32x4 acc[4][4];
#pragma unroll
  for (int i = 0; i < 4; ++i)
#pragma unroll
    for (int j = 0; j < 4; ++j) acc[i][j] = (f32x4){0.f, 0.f, 0.f, 0.f};

  const int q0 = tid;
  const int q1 = tid + 256;
  // stage source: row = q>>2, chunk = (q&3) ^ ((q>>3)&3)  [swizzle inverse]
  const short* ga0 =
      A + (size_t)(m0 + (q0 >> 2)) * K + ((q0 & 3) ^ ((q0 >> 3) & 3)) * 8;
  const short* ga1 =
      A + (size_t)(m0 + (q1 >> 2)) * K + ((q1 & 3) ^ ((q1 >> 3) & 3)) * 8;
  const short* gb0 =
      B + (size_t)(n0 + (q0 >> 2)) * K + ((q0 & 3) ^ ((q0 >> 3) & 3)) * 8;
  const short* gb1 =
      B + (size_t)(n0 + (q1 >> 2)) * K + ((q1 & 3) ^ ((q1 >> 3) & 3)) * 8;
  short* la0 = &aT[q0 * 8];
  short* la1 = &aT[q1 * 8];
  short* lb0 = &bT[q0 * 8];
  short* lb1 = &bT[q1 * 8];

  // read offsets: slot = (lane>>4) ^ ((lm>>1)&3)   [swizzle forward]
  const int slot = ((lane >> 4) ^ ((lm >> 1) & 3)) * 8;
  int aoff[4], boff[4];
#pragma unroll
  for (int t = 0; t < 4; ++t) {
    aoff[t] = (wm + t * 16 + lm) * 32 + slot;
    boff[t] = (wn + t * 16 + lm) * 32 + slot;
  }

  // prologue: stage K-tile 0 into buffer 0
  ASYNC_CP(ga0, la0);
  ASYNC_CP(ga1, la1);
  ASYNC_CP(gb0, lb0);
  ASYNC_CP(gb1, lb1);

  int so = 128 * 32;   // stage offset (shorts): buffer for tile t+1
  int ro = 0;          // read offset: buffer holding tile t
  for (int k0 = 32; k0 < K; k0 += 32) {
    // barrier implies vmcnt(0)+lgkmcnt(0): stage(ro) complete, and all waves
    // finished reading buffer 'so' last iteration -> safe to overwrite.
    __syncthreads();
    ASYNC_CP(ga0 + k0, la0 + so);
    ASYNC_CP(ga1 + k0, la1 + so);
    ASYNC_CP(gb0 + k0, lb0 + so);
    ASYNC_CP(gb1 + k0, lb1 + so);
    bf16x8 af[4], bfr[4];
#pragma unroll
    for (int t = 0; t < 4; ++t) {
      af[t] = __builtin_bit_cast(bf16x8, *(const s16x8*)&aT[ro + aoff[t]]);
      bfr[t] = __builtin_bit_cast(bf16x8, *(const s16x8*)&bT[ro + boff[t]]);
    }
#pragma unroll
    for (int i = 0; i < 4; ++i)
#pragma unroll
      for (int j = 0; j < 4; ++j)
        acc[i][j] = __builtin_amdgcn_mfma_f32_16x16x32_bf16(af[i], bfr[j],
                                                            acc[i][j], 0, 0, 0);
    so ^= 128 * 32;
    ro ^= 128 * 32;
  }
  // final tile (no prefetch)
  __syncthreads();
  {
    bf16x8 af[4], bfr[4];
#pragma unroll
    for (int t = 0; t < 4; ++t) {
      af[t] = __builtin_bit_cast(bf16x8, *(const s16x8*)&aT[ro + aoff[t]]);
      bfr[t] = __builtin_bit_cast(bf16x8, *(const s16x8*)&bT[ro + boff[t]]);
    }
#pragma unroll
    for (int i = 0; i < 4; ++i)
#pragma unroll
      for (int j = 0; j < 4; ++j)
        acc[i][j] = __builtin_amdgcn_mfma_f32_16x16x32_bf16(af[i], bfr[j],
                                                            acc[i][j], 0, 0, 0);
  }

  // epilogue: C/D layout col=lane&15, row=(lane>>4)*4+reg  [m89-verified]
  // + fused per-channel sum / sumsq partials for BN (rows < M_stat)
#pragma unroll
  for (int j = 0; j < 4; ++j) {
    const int colg = n0 + wn + j * 16 + lm;
    const float bv = bias[colg];
    float cs = 0.f, cq = 0.f;
#pragma unroll
    for (int i = 0; i < 4; ++i) {
      const int rbase = m0 + wm + i * 16 + (lane >> 4) * 4;
#pragma unroll
      for (int r = 0; r < 4; ++r) {
        const int row = rbase + r;
        const float v = acc[i][j][r] + bv;
        if (row < M_stat) {
          cs += v;
          cq += v * v;
        }
        if (row < M_store) {
          if (BF16OUT)
            ((short*)outp)[(size_t)row * HS + colg] = f2bf(v);
          else
            ((float*)outp)[(size_t)row * HS + colg] = v;
        }
      }
    }
    cs += __shfl_xor(cs, 16);
    cs += __shfl_xor(cs, 32);
    cq += __shfl_xor(cq, 16);
    cq += __shfl_xor(cq, 32);
    if ((lane >> 4) == 0) {
      atomicAdd(&sums[colg], cs);
      atomicAdd(&sums[HS + colg], cq);
    }
  }
}

// ---------------------------------------------------------------------------
// 8) BN finalize: per-channel scale/shift from sums
// ---------------------------------------------------------------------------
__global__ void finalize_kernel(const float* __restrict__ sums,
                                const float* __restrict__ gamma,
                                const float* __restrict__ beta,
                                float* __restrict__ scsh) {
  int c = blockIdx.x * 256 + threadIdx.x;   // grid 4 x 256 = 1024
  const float inv = 1.f / (float)N_NODES;
  float m = sums[c] * inv;
  float var = sums[HS + c] * inv - m * m;   // biased var, matches reference
  float sc = gamma[c] / sqrtf(var + EPS_BN);
  scsh[c] = sc;
  scsh[HS + c] = beta[c] - m * sc;
}

// ---------------------------------------------------------------------------
// 9) BN apply (in place). bf16 variant adds ReLU (layer 1).
// ---------------------------------------------------------------------------
__global__ __launch_bounds__(256) void bn_relu_bf16_kernel(
    short* __restrict__ y, const float* __restrict__ scsh) {
  size_t base = (size_t)blockIdx.x * HS + threadIdx.x * 4;
  int c = threadIdx.x * 4;
  s16x4 v = *(s16x4*)&y[base];
  s16x4 o;
#pragma unroll
  for (int k = 0; k < 4; ++k) {
    float f = bf2f(v[k]) * scsh[c + k] + scsh[HS + c + k];
    o[k] = f2bf(fmaxf(f, 0.f));
  }
  *(s16x4*)&y[base] = o;
}

__global__ __launch_bounds__(256) void bn_f32_kernel(
    float* __restrict__ y, const float* __restrict__ scsh) {
  size_t base = (size_t)blockIdx.x * HS + threadIdx.x * 4;
  int c = threadIdx.x * 4;
  float4 v = *(float4*)&y[base];
  const float4 sc = *(const float4*)&scsh[c];
  const float4 sh = *(const float4*)&scsh[HS + c];
  v.x = v.x * sc.x + sh.x;
  v.y = v.y * sc.y + sh.y;
  v.z = v.z * sc.z + sh.z;
  v.w = v.w * sc.w + sh.w;
  *(float4*)&y[base] = v;
}

// ---------------------------------------------------------------------------
extern "C" void kernel_launch(void* const* d_in, const int* in_sizes, int n_in,
                              void* d_out, int out_size, void* d_ws,
                              size_t ws_size, hipStream_t stream) {
  const float* x = (const float*)d_in[0];
  const float* ea = (const float*)d_in[1];
  const float* u = (const float*)d_in[2];
  const float* w1 = (const float*)d_in[3];
  const float* b1 = (const float*)d_in[4];
  const float* g1 = (const float*)d_in[5];
  const float* be1 = (const float*)d_in[6];
  const float* w2 = (const float*)d_in[7];
  const float* b2 = (const float*)d_in[8];
  const float* g2 = (const float*)d_in[9];
  const float* be2 = (const float*)d_in[10];
  const int* ei = (const int*)d_in[11];
  const int* batch = (const int*)d_in[12];
  float* out = (float*)d_out;
  const int* col = ei + N_EDGES;   // edge_index[1]

  // ---- workspace layout ----
  char* ws = (char*)d_ws;
  float* sums1 = (float*)ws;                     // 2048
  float* sums2 = sums1 + 2048;                   // 2048
  int* hist = (int*)(sums2 + 2048);              // NSCAN
  int* bsum = hist + NSCAN;                      // 256
  // ---- end of zero region ----
  size_t zero_bytes = (size_t)((char*)(bsum + 256) - ws);
  float* scsh = (float*)(bsum + 256);            // 2048
  int* starts = (int*)(scsh + 2048);             // NSCAN
  int* cursor = starts + NSCAN;                  // NSCAN
  int* boff = cursor + NSCAN;                    // 256
  int* sortedEid = boff + 256;                   // N_EDGES
  char* hraw = (char*)(sortedEid + N_EDGES);
  short* h = (short*)(((uintptr_t)hraw + 255) & ~(uintptr_t)255);
  short* w1b = h + (size_t)M_PAD * CIN;
  short* w2b = w1b + (size_t)HS * CIN;
  short* y1 = w2b + (size_t)HS * HS;

  hipMemsetAsync(ws, 0, zero_bytes, stream);

  // edge bucketing
  hist_kernel<<<N_EDGES / 256, 256, 0, stream>>>(col, hist);
  scan1_kernel<<<NSCAN / 256, 256, 0, stream>>>(hist, starts, bsum);
  scan2_kernel<<<1, 256, 0, stream>>>(bsum, boff);
  scan3_kernel<<<NSCAN / 256, 256, 0, stream>>>(starts, boff, cursor);
  place_kernel<<<N_EDGES / 256, 256, 0, stream>>>(col, cursor, sortedEid);

  // h assembly
  cast_x_kernel<<<N_NODES * 128 / 256, 256, 0, stream>>>(x, h);
  cast_u_kernel<<<N_NODES * 32 / 256, 256, 0, stream>>>(u, batch, h);
  pad_kernel<<<20, 256, 0, stream>>>(h);
  edge_reduce_kernel<<<N_NODES / 4, 256, 0, stream>>>(ea, sortedEid, hist,
                                                      starts, h);
  cast2_kernel<<<HS * HS / 256, 256, 0, stream>>>(w1, w2, w1b, w2b);

  // layer 1
  gemm_bt<true><<<dim3(8, M_PAD / 128), 256, 0, stream>>>(
      h, w1b, b1, y1, CIN, M_PAD, N_NODES, sums1);
  finalize_kernel<<<4, 256, 0, stream>>>(sums1, g1, be1, scsh);
  bn_relu_bf16_kernel<<<N_NODES, 256, 0, stream>>>(y1, scsh);

  // layer 2
  gemm_bt<false><<<dim3(8, M_PAD / 128), 256, 0, stream>>>(
      y1, w2b, b2, out, HS, N_NODES, N_NODES, sums2);
  finalize_kernel<<<4, 256, 0, stream>>>(sums2, g2, be2, scsh);
  bn_f32_kernel<<<N_NODES, 256, 0, stream>>>(out, scsh);
}

// Round 5
// 925.564 us; speedup vs baseline: 1.1489x; 1.0160x over previous
//
#include <hip/hip_runtime.h>

// Problem constants (from reference setup_inputs)
#define N_NODES 50000
#define N_EDGES 800000
#define XF 512
#define EF 64
#define UF 128
#define HS 1024
#define CIN 832           // 512 + 3*64 + 128
#define EPS_BN 1e-5f
#define M_PAD 50176       // 196 * 256  (GEMM row padding, 256-tile)
#define NSCAN 50176       // 196 * 256  (scan padding)

typedef __bf16 bf16x8 __attribute__((ext_vector_type(8)));
typedef short s16x8 __attribute__((ext_vector_type(8)));
typedef short s16x4 __attribute__((ext_vector_type(4)));
typedef float f32x4 __attribute__((ext_vector_type(4)));

__device__ __forceinline__ short f2bf(float f) {
  unsigned u = __float_as_uint(f);
  u += 0x7FFFu + ((u >> 16) & 1u);   // round-to-nearest-even (finite inputs)
  return (short)(u >> 16);
}
__device__ __forceinline__ float bf2f(short s) {
  return __uint_as_float(((unsigned)(unsigned short)s) << 16);
}

// async global->LDS, 16B per lane; LDS dest must be uniform-base + lane*16
#define ASYNC_CP(gp, lp)                                                      \
  __builtin_amdgcn_global_load_lds(                                           \
      (__attribute__((address_space(1))) void*)(gp),                          \
      (__attribute__((address_space(3))) void*)(lp), 16, 0, 0)

// ---------------------------------------------------------------------------
// 1) Edge histogram over destination node (int atomics, 1 per edge)
// ---------------------------------------------------------------------------
__global__ void hist_kernel(const int* __restrict__ col,
                            int* __restrict__ hist) {
  int e = blockIdx.x * 256 + threadIdx.x;   // grid exactly E
  atomicAdd(&hist[col[e]], 1);
}

// ---------------------------------------------------------------------------
// 2) 3-phase exclusive scan over NSCAN counts
// ---------------------------------------------------------------------------
__global__ void scan1_kernel(const int* __restrict__ hist,
                             int* __restrict__ starts,
                             int* __restrict__ bsum) {
  __shared__ int tmp[256];
  int i = blockIdx.x * 256 + threadIdx.x;
  int v = hist[i];
  tmp[threadIdx.x] = v;
  __syncthreads();
#pragma unroll
  for (int o = 1; o < 256; o <<= 1) {
    int t = (threadIdx.x >= o) ? tmp[threadIdx.x - o] : 0;
    __syncthreads();
    tmp[threadIdx.x] += t;
    __syncthreads();
  }
  starts[i] = tmp[threadIdx.x] - v;   // exclusive
  if (threadIdx.x == 255) bsum[blockIdx.x] = tmp[255];
}

__global__ void scan2_kernel(const int* __restrict__ bsum,
                             int* __restrict__ boff) {
  __shared__ int tmp[256];
  int v = (threadIdx.x < NSCAN / 256) ? bsum[threadIdx.x] : 0;
  tmp[threadIdx.x] = v;
  __syncthreads();
#pragma unroll
  for (int o = 1; o < 256; o <<= 1) {
    int t = (threadIdx.x >= o) ? tmp[threadIdx.x - o] : 0;
    __syncthreads();
    tmp[threadIdx.x] += t;
    __syncthreads();
  }
  boff[threadIdx.x] = tmp[threadIdx.x] - v;
}

__global__ void scan3_kernel(int* __restrict__ starts,
                             const int* __restrict__ boff,
                             int* __restrict__ cursor) {
  int i = blockIdx.x * 256 + threadIdx.x;
  int s = starts[i] + boff[blockIdx.x];
  starts[i] = s;
  cursor[i] = s;
}

// ---------------------------------------------------------------------------
// 3) Placement: edge ids sorted (bucketed) by destination node
// ---------------------------------------------------------------------------
__global__ void place_kernel(const int* __restrict__ col,
                             int* __restrict__ cursor,
                             int* __restrict__ sortedEid) {
  int e = blockIdx.x * 256 + threadIdx.x;   // grid exactly E
  int c = col[e];
  int pos = atomicAdd(&cursor[c], 1);
  sortedEid[pos] = e;
}

// ---------------------------------------------------------------------------
// 4) Segmented reduce: one wave per node; lane = feature. Preload up to 64
//    edge ids lane-parallel, shfl-broadcast, unroll x4 (4 loads in flight).
// ---------------------------------------------------------------------------
__global__ __launch_bounds__(256) void edge_reduce_kernel(
    const float* __restrict__ ea, const int* __restrict__ sortedEid,
    const int* __restrict__ hist, const int* __restrict__ starts,
    short* __restrict__ h) {
  int node = blockIdx.x * 4 + (threadIdx.x >> 6);   // grid 12500 -> node<50000
  int lane = threadIdx.x & 63;
  int deg = hist[node];
  int st = starts[node];
  float s = 0.f, mx = -3.0e38f;
  for (int base = 0; base < deg; base += 64) {
    int nc = deg - base;
    if (nc > 64) nc = 64;
    int el = (lane < nc) ? sortedEid[st + base + lane] : 0;
    int i = 0;
    for (; i + 4 <= nc; i += 4) {
      int e0 = __shfl(el, i);
      int e1 = __shfl(el, i + 1);
      int e2 = __shfl(el, i + 2);
      int e3 = __shfl(el, i + 3);
      float v0 = ea[(size_t)e0 * EF + lane];
      float v1 = ea[(size_t)e1 * EF + lane];
      float v2 = ea[(size_t)e2 * EF + lane];
      float v3 = ea[(size_t)e3 * EF + lane];
      s += (v0 + v1) + (v2 + v3);
      mx = fmaxf(mx, fmaxf(fmaxf(v0, v1), fmaxf(v2, v3)));
    }
    for (; i < nc; ++i) {
      int e = __shfl(el, i);
      float v = ea[(size_t)e * EF + lane];
      s += v;
      mx = fmaxf(mx, v);
    }
  }
  size_t base = (size_t)node * CIN;
  h[base + 640 + lane] = f2bf(deg ? mx : 0.f);
  h[base + 704 + lane] = f2bf(deg ? s / (float)deg : 0.f);
  h[base + 768 + lane] = f2bf(s);
}

// ---------------------------------------------------------------------------
// 5) h assembly, flat fully-coalesced kernels
// ---------------------------------------------------------------------------
__global__ __launch_bounds__(256) void cast_x_kernel(
    const float* __restrict__ x, short* __restrict__ h) {
  int idx = blockIdx.x * 256 + threadIdx.x;   // grid 25000 -> N_NODES*128
  int n = idx >> 7;
  int c4 = (idx & 127) * 4;
  const float4 v = *(const float4*)&x[(size_t)n * XF + c4];
  *(s16x4*)&h[(size_t)n * CIN + c4] =
      (s16x4){f2bf(v.x), f2bf(v.y), f2bf(v.z), f2bf(v.w)};
}

__global__ __launch_bounds__(256) void cast_u_kernel(
    const float* __restrict__ u, const int* __restrict__ batch,
    short* __restrict__ h) {
  int idx = blockIdx.x * 256 + threadIdx.x;   // grid 6250 -> N_NODES*32
  int n = idx >> 5;
  int c4 = (idx & 31) * 4;
  const float4 v = *(const float4*)&u[(size_t)batch[n] * UF + c4];
  *(s16x4*)&h[(size_t)n * CIN + XF + c4] =
      (s16x4){f2bf(v.x), f2bf(v.y), f2bf(v.z), f2bf(v.w)};
}

__global__ void pad_kernel(short* __restrict__ h) {
  int idx = blockIdx.x * 256 + threadIdx.x;   // 176 pad rows * 832 / 8
  if (idx < (M_PAD - N_NODES) * CIN / 8)
    *(s16x8*)&h[(size_t)N_NODES * CIN + (size_t)idx * 8] =
        (s16x8){0, 0, 0, 0, 0, 0, 0, 0};
}

// ---------------------------------------------------------------------------
// 6) fp32 -> bf16 weight cast (both weights in one launch)
// ---------------------------------------------------------------------------
__global__ void cast2_kernel(const float* __restrict__ w1,
                             const float* __restrict__ w2,
                             short* __restrict__ o1, short* __restrict__ o2) {
  int i = blockIdx.x * 256 + threadIdx.x;   // grid HS*HS/256
  if (i < HS * CIN) o1[i] = f2bf(w1[i]);
  o2[i] = f2bf(w2[i]);
}

// ---------------------------------------------------------------------------
// 7) GEMM, 256x256 8-phase template (T3+T4+T2+T5, m201-style, plain HIP).
//    C[M,1024] = A[M,K] @ B[1024,K]^T + bias, bf16 in, fused BN stats.
//    8 waves (512 thr), per-wave C = 128x64 (acc[8][4] of 16x16 frags).
//    LDS 128 KiB dynamic: A[2][256][64] @ 0, B[2][256][64] @ 32768 shorts.
//    K-loop: 8 phases / 2 K-tiles per iter; counted vmcnt only at ph4/ph8.
//    LDS XOR swizzle (T2): 16B slot s at row r holds global chunk s^(r&7);
//    stage-side global source pre-swizzled, read-side applies same XOR.
//    Hazard ledger (why each stage placement is safe):
//      buf B fully read after ph2/ph6; buf A fully read after ph3/ph7.
//      iter t stages: ph1,2 -> tile 2t+1 A (buf1, read last at prev ph7);
//      ph3,4 -> tile 2t+2 B (buf0 B read by ph2); ph5,6 -> tile 2t+2 A
//      (buf0 A read by ph3); ph7,8 -> tile 2t+3 B (buf1 B read by ph6).
//      vmcnt(4) at ph4 leaves only ph3-4's loads in flight => tile 2t+1
//      fully landed before ph5 reads buf1; vmcnt(4) at ph8 leaves only
//      ph7-8's => tile 2t+2 landed before next ph1 reads buf0. Last iter
//      drains (vmcnt(0)); odd K-tile count peels a barrier-free tail.
// ---------------------------------------------------------------------------
#define BARF()                                                                \
  do {                                                                        \
    asm volatile("" ::: "memory");                                            \
    __builtin_amdgcn_s_barrier();                                             \
    asm volatile("" ::: "memory");                                            \
  } while (0)
#define WV4() asm volatile("s_waitcnt vmcnt(4)" ::: "memory")
#define WV0() asm volatile("s_waitcnt vmcnt(0)" ::: "memory")

#define STAGE_A(BUF, H, KT)                                                   \
  do {                                                                        \
    ASYNC_CP(pa + (size_t)((H)*128 + 0) * K + (KT)*64,                        \
             &lds[(BUF)*16384 + (H)*8192 + 0 + tid * 8]);                     \
    ASYNC_CP(pa + (size_t)((H)*128 + 64) * K + (KT)*64,                       \
             &lds[(BUF)*16384 + (H)*8192 + 4096 + tid * 8]);                  \
  } while (0)
#define STAGE_B(BUF, H, KT)                                                   \
  do {                                                                        \
    ASYNC_CP(pb + (size_t)((H)*128 + 0) * K + (KT)*64,                        \
             &lds[32768 + (BUF)*16384 + (H)*8192 + 0 + tid * 8]);             \
    ASYNC_CP(pb + (size_t)((H)*128 + 64) * K + (KT)*64,                       \
             &lds[32768 + (BUF)*16384 + (H)*8192 + 4096 + tid * 8]);          \
  } while (0)

#define LDA(BUF, IH)                                                          \
  do {                                                                        \
    _Pragma("unroll") for (int f_ = 0; f_ < 4; ++f_)                          \
        _Pragma("unroll") for (int k_ = 0; k_ < 2; ++k_) ar[f_][k_] =         \
        __builtin_bit_cast(                                                   \
            bf16x8,                                                           \
            *(const s16x8*)&lds[(BUF)*16384 + (IH)*4096 + aoff[f_][k_]]);     \
  } while (0)
#define LDB(BUF, JH)                                                          \
  do {                                                                        \
    _Pragma("unroll") for (int j_ = 0; j_ < 2; ++j_)                          \
        _Pragma("unroll") for (int k_ = 0; k_ < 2; ++k_)                      \
            br[(JH)*2 + j_][k_] = __builtin_bit_cast(                         \
        bf16x8,                                                               \
        *(const s16x8*)&lds[(BUF)*16384 + (JH)*2048 + boff[j_][k_]]);         \
  } while (0)
#define MM(IH, JH)                                                            \
  do {                                                                        \
    __builtin_amdgcn_s_setprio(1);                                            \
    _Pragma("unroll") for (int f_ = 0; f_ < 4; ++f_)                          \
        _Pragma("unroll") for (int j_ = 0; j_ < 2; ++j_)                      \
            _Pragma("unroll") for (int k_ = 0; k_ < 2; ++k_)                  \
                acc[(IH)*4 + f_][(JH)*2 + j_] =                               \
        __builtin_amdgcn_mfma_f32_16x16x32_bf16(                              \
            ar[f_][k_], br[(JH)*2 + j_][k_],                                  \
            acc[(IH)*4 + f_][(JH)*2 + j_], 0, 0, 0);                          \
    __builtin_amdgcn_s_setprio(0);                                            \
  } while (0)

template <bool BF16OUT>
__global__ __launch_bounds__(512, 2) void gemm8(
    const short* __restrict__ A, const short* __restrict__ B,
    const float* __restrict__ bias, void* __restrict__ outp, int K,
    int M_store, int M_stat, float* __restrict__ sums) {
  extern __shared__ short lds[];   // 131072 B
  const int tid = threadIdx.x;
  const int lane = tid & 63;
  const int wave = tid >> 6;
  const int wr = wave >> 2;        // 0..1
  const int wc = wave & 3;         // 0..3
  const int lm = lane & 15;
  const int lg = lane >> 4;        // 0..3

  // XCD-aware bijective swizzle: nwg = 4*196 = 784 = 8*98
  const int cpx = (gridDim.x * gridDim.y) >> 3;   // 98
  const int l = blockIdx.y * gridDim.x + blockIdx.x;
  const int g = (l & 7) * cpx + (l >> 3);
  const int m0 = (g >> 2) * 256;
  const int n0 = (g & 3) * 256;

  f32x4 acc[8][4];
#pragma unroll
  for (int i = 0; i < 8; ++i)
#pragma unroll
    for (int j = 0; j < 4; ++j) acc[i][j] = (f32x4){0.f, 0.f, 0.f, 0.f};

  // staging addresses: thread q -> local row q>>3, slot q&7;
  // global chunk = (q&7) ^ ((q>>3)&7)  [inverse swizzle, rule #21]
  const int srow = tid >> 3;
  const int sx = ((tid & 7) ^ (srow & 7)) * 8;
  const short* pa = A + (size_t)(m0 + srow) * K + sx;
  const short* pb = B + (size_t)(n0 + srow) * K + sx;

  // reader LDS offsets (shorts): row*64 + (chunk ^ (row&7))*8, row&7 == lm&7
  int aoff[4][2], boff[4][2];
#pragma unroll
  for (int f = 0; f < 4; ++f)
#pragma unroll
    for (int kk = 0; kk < 2; ++kk)
      aoff[f][kk] =
          (wr * 128 + f * 16 + lm) * 64 + ((kk * 4 + lg) ^ (lm & 7)) * 8;
#pragma unroll
  for (int jj = 0; jj < 2; ++jj)
#pragma unroll
    for (int kk = 0; kk < 2; ++kk)
      boff[jj][kk] = 32768 + (wc * 64 + jj * 16 + lm) * 64 +
                     ((kk * 4 + lg) ^ (lm & 7)) * 8;

  bf16x8 ar[4][2], br[4][2];

  const int NT = K >> 6;        // K-tiles (13 or 16)
  const int T = NT >> 1;        // main iterations
  const bool odd = NT & 1;

  // prologue: tile0 (B0,B1,A0,A1 -> buf0), tile1 B (->buf1): 12 loads
  STAGE_B(0, 0, 0);
  STAGE_B(0, 1, 0);
  STAGE_A(0, 0, 0);
  STAGE_A(0, 1, 0);
  STAGE_B(1, 0, 1);
  STAGE_B(1, 1, 1);
  WV4();   // tile0's 8 loads landed; tile1.B may remain in flight
  BARF();

  for (int t = 0; t < T; ++t) {
    const int kp0 = 2 * t + 2, kp1 = 2 * t + 3;
    const bool s0 = kp0 < NT, s1 = kp1 < NT;
    const bool last = (t == T - 1);
    // ph1: compute buf0 Q(0,0); stage tile 2t+1 A-half0 -> buf1
    LDA(0, 0);
    LDB(0, 0);
    STAGE_A(1, 0, 2 * t + 1);
    BARF();
    MM(0, 0);
    BARF();
    // ph2: Q(0,1); stage tile 2t+1 A-half1 -> buf1
    LDB(0, 1);
    STAGE_A(1, 1, 2 * t + 1);
    BARF();
    MM(0, 1);
    BARF();
    // ph3: Q(1,0); stage tile 2t+2 B-half0 -> buf0 (buf0 B read by ph2)
    LDA(0, 1);
    if (s0) STAGE_B(0, 0, kp0);
    BARF();
    MM(1, 0);
    BARF();
    // ph4: Q(1,1); stage tile 2t+2 B-half1; counted wait covers ph5 reads
    if (s0) STAGE_B(0, 1, kp0);
    if (last && !odd) WV0();
    else WV4();
    BARF();
    MM(1, 1);
    BARF();
    // ph5: compute buf1 Q(0,0); stage tile 2t+2 A-half0 -> buf0
    LDA(1, 0);
    LDB(1, 0);
    if (s0) STAGE_A(0, 0, kp0);
    BARF();
    MM(0, 0);
    BARF();
    // ph6: Q(0,1); stage tile 2t+2 A-half1 -> buf0
    LDB(1, 1);
    if (s0) STAGE_A(0, 1, kp0);
    BARF();
    MM(0, 1);
    BARF();
    // ph7: Q(1,0); stage tile 2t+3 B-half0 -> buf1 (buf1 B read by ph6)
    LDA(1, 1);
    if (s1) STAGE_B(1, 0, kp1);
    BARF();
    MM(1, 0);
    BARF();
    // ph8: Q(1,1); stage tile 2t+3 B-half1; counted wait covers next ph1
    if (s1) STAGE_B(1, 1, kp1);
    if (!last) WV4();
    else if (odd) WV0();
    BARF();
    MM(1, 1);
    BARF();
  }
  if (odd) {   // tail tile NT-1 in buf0 (staged iter T-1 ph3-6, drained ph8)
    LDA(0, 0);
    LDB(0, 0);
    MM(0, 0);
    LDB(0, 1);
    MM(0, 1);
    LDA(0, 1);
    MM(1, 0);
    MM(1, 1);
  }

  // epilogue: C/D layout col=lane&15, row=(lane>>4)*4+reg  [m89-verified]
  // + fused per-channel sum / sumsq partials for BN (rows < M_stat)
#pragma unroll
  for (int j = 0; j < 4; ++j) {
    const int colg = n0 + wc * 64 + j * 16 + lm;
    const float bv = bias[colg];
    float cs = 0.f, cq = 0.f;
#pragma unroll
    for (int i = 0; i < 8; ++i) {
      const int rbase = m0 + wr * 128 + i * 16 + lg * 4;
#pragma unroll
      for (int r = 0; r < 4; ++r) {
        const int row = rbase + r;
        const float v = acc[i][j][r] + bv;
        if (row < M_stat) {
          cs += v;
          cq += v * v;
        }
        if (row < M_store) {
          if (BF16OUT)
            ((short*)outp)[(size_t)row * HS + colg] = f2bf(v);
          else
            ((float*)outp)[(size_t)row * HS + colg] = v;
        }
      }
    }
    cs += __shfl_xor(cs, 16);
    cs += __shfl_xor(cs, 32);
    cq += __shfl_xor(cq, 16);
    cq += __shfl_xor(cq, 32);
    if (lg == 0) {
      atomicAdd(&sums[colg], cs);
      atomicAdd(&sums[HS + colg], cq);
    }
  }
}

// ---------------------------------------------------------------------------
// 8) BN finalize: per-channel scale/shift from sums
// ---------------------------------------------------------------------------
__global__ void finalize_kernel(const float* __restrict__ sums,
                                const float* __restrict__ gamma,
                                const float* __restrict__ beta,
                                float* __restrict__ scsh) {
  int c = blockIdx.x * 256 + threadIdx.x;   // grid 4 x 256 = 1024
  const float inv = 1.f / (float)N_NODES;
  float m = sums[c] * inv;
  float var = sums[HS + c] * inv - m * m;   // biased var, matches reference
  float sc = gamma[c] / sqrtf(var + EPS_BN);
  scsh[c] = sc;
  scsh[HS + c] = beta[c] - m * sc;
}

// ---------------------------------------------------------------------------
// 9) BN apply (in place). bf16 variant adds ReLU (layer 1).
// ---------------------------------------------------------------------------
__global__ __launch_bounds__(256) void bn_relu_bf16_kernel(
    short* __restrict__ y, const float* __restrict__ scsh) {
  size_t base = (size_t)blockIdx.x * HS + threadIdx.x * 4;
  int c = threadIdx.x * 4;
  s16x4 v = *(s16x4*)&y[base];
  s16x4 o;
#pragma unroll
  for (int k = 0; k < 4; ++k) {
    float f = bf2f(v[k]) * scsh[c + k] + scsh[HS + c + k];
    o[k] = f2bf(fmaxf(f, 0.f));
  }
  *(s16x4*)&y[base] = o;
}

__global__ __launch_bounds__(256) void bn_f32_kernel(
    float* __restrict__ y, const float* __restrict__ scsh) {
  size_t base = (size_t)blockIdx.x * HS + threadIdx.x * 4;
  int c = threadIdx.x * 4;
  float4 v = *(float4*)&y[base];
  const float4 sc = *(const float4*)&scsh[c];
  const float4 sh = *(const float4*)&scsh[HS + c];
  v.x = v.x * sc.x + sh.x;
  v.y = v.y * sc.y + sh.y;
  v.z = v.z * sc.z + sh.z;
  v.w = v.w * sc.w + sh.w;
  *(float4*)&y[base] = v;
}

// ---------------------------------------------------------------------------
extern "C" void kernel_launch(void* const* d_in, const int* in_sizes, int n_in,
                              void* d_out, int out_size, void* d_ws,
                              size_t ws_size, hipStream_t stream) {
  const float* x = (const float*)d_in[0];
  const float* ea = (const float*)d_in[1];
  const float* u = (const float*)d_in[2];
  const float* w1 = (const float*)d_in[3];
  const float* b1 = (const float*)d_in[4];
  const float* g1 = (const float*)d_in[5];
  const float* be1 = (const float*)d_in[6];
  const float* w2 = (const float*)d_in[7];
  const float* b2 = (const float*)d_in[8];
  const float* g2 = (const float*)d_in[9];
  const float* be2 = (const float*)d_in[10];
  const int* ei = (const int*)d_in[11];
  const int* batch = (const int*)d_in[12];
  float* out = (float*)d_out;
  const int* col = ei + N_EDGES;   // edge_index[1]

  // one-time: allow 128 KiB dynamic LDS on the GEMM
  static bool attr_done = false;
  if (!attr_done) {
    hipFuncSetAttribute(reinterpret_cast<const void*>(&gemm8<true>),
                        hipFuncAttributeMaxDynamicSharedMemorySize, 131072);
    hipFuncSetAttribute(reinterpret_cast<const void*>(&gemm8<false>),
                        hipFuncAttributeMaxDynamicSharedMemorySize, 131072);
    attr_done = true;
  }

  // ---- workspace layout ----
  char* ws = (char*)d_ws;
  float* sums1 = (float*)ws;                     // 2048
  float* sums2 = sums1 + 2048;                   // 2048
  int* hist = (int*)(sums2 + 2048);              // NSCAN
  int* bsum = hist + NSCAN;                      // 256
  // ---- end of zero region ----
  size_t zero_bytes = (size_t)((char*)(bsum + 256) - ws);
  float* scsh = (float*)(bsum + 256);            // 2048
  int* starts = (int*)(scsh + 2048);             // NSCAN
  int* cursor = starts + NSCAN;                  // NSCAN
  int* boff = cursor + NSCAN;                    // 256
  int* sortedEid = boff + 256;                   // N_EDGES
  char* hraw = (char*)(sortedEid + N_EDGES);
  short* h = (short*)(((uintptr_t)hraw + 255) & ~(uintptr_t)255);
  short* w1b = h + (size_t)M_PAD * CIN;
  short* w2b = w1b + (size_t)HS * CIN;
  short* y1 = w2b + (size_t)HS * HS;

  hipMemsetAsync(ws, 0, zero_bytes, stream);

  // edge bucketing
  hist_kernel<<<N_EDGES / 256, 256, 0, stream>>>(col, hist);
  scan1_kernel<<<NSCAN / 256, 256, 0, stream>>>(hist, starts, bsum);
  scan2_kernel<<<1, 256, 0, stream>>>(bsum, boff);
  scan3_kernel<<<NSCAN / 256, 256, 0, stream>>>(starts, boff, cursor);
  place_kernel<<<N_EDGES / 256, 256, 0, stream>>>(col, cursor, sortedEid);

  // h assembly
  cast_x_kernel<<<N_NODES * 128 / 256, 256, 0, stream>>>(x, h);
  cast_u_kernel<<<N_NODES * 32 / 256, 256, 0, stream>>>(u, batch, h);
  pad_kernel<<<((M_PAD - N_NODES) * CIN / 8 + 255) / 256, 256, 0, stream>>>(h);
  edge_reduce_kernel<<<N_NODES / 4, 256, 0, stream>>>(ea, sortedEid, hist,
                                                      starts, h);
  cast2_kernel<<<HS * HS / 256, 256, 0, stream>>>(w1, w2, w1b, w2b);

  // layer 1
  gemm8<true><<<dim3(4, M_PAD / 256), 512, 131072, stream>>>(
      h, w1b, b1, y1, CIN, M_PAD, N_NODES, sums1);
  finalize_kernel<<<4, 256, 0, stream>>>(sums1, g1, be1, scsh);
  bn_relu_bf16_kernel<<<N_NODES, 256, 0, stream>>>(y1, scsh);

  // layer 2
  gemm8<false><<<dim3(4, M_PAD / 256), 512, 131072, stream>>>(
      y1, w2b, b2, out, HS, N_NODES, N_NODES, sums2);
  finalize_kernel<<<4, 256, 0, stream>>>(sums2, g2, be2, scsh);
  bn_f32_kernel<<<N_NODES, 256, 0, stream>>>(out, scsh);
}